// Round 6
// baseline (396.934 us; speedup 1.0000x reference)
//
#include <hip/hip_runtime.h>
#include <cstdint>

#define V_ 25
#define T_ 128
#define VT_ 3200
#define NVTF_ 204800.0f

typedef unsigned short ushort_t;
typedef __attribute__((ext_vector_type(8))) short s16x8;
typedef __attribute__((ext_vector_type(4))) short s16x4;
typedef __attribute__((ext_vector_type(4))) float f32x4;

__device__ __forceinline__ ushort_t f2bf(float f) {
    union { float f; unsigned u; } v; v.f = f;
    unsigned r = v.u + 0x7FFFu + ((v.u >> 16) & 1u);
    return (ushort_t)(r >> 16);
}
__device__ __forceinline__ float bf2f(ushort_t h) {
    union { unsigned u; float f; } v; v.u = ((unsigned)h) << 16;
    return v.f;
}
__device__ __forceinline__ void gload16(const void* g, void* l) {
    __builtin_amdgcn_global_load_lds((const __attribute__((address_space(1))) void*)g,
                                     (__attribute__((address_space(3))) void*)l, 16, 0, 0);
}

// ---------------- k_a: a1/a2 = wg @ x (bf16 out) + xb bf16 [v*T+t][64] ----------------
__global__ __launch_bounds__(128) void k_a(const float* __restrict__ x,
        const float* __restrict__ wg1, const float* __restrict__ wg2,
        ushort_t* __restrict__ a1, ushort_t* __restrict__ a2,
        ushort_t* __restrict__ xb) {
    int b = blockIdx.x; int n = b / V_; int v = b % V_;
    int t = threadIdx.x;
    __shared__ float w1s[1024], w2s[1024];
    for (int i = threadIdx.x; i < 1024; i += 128) { w1s[i] = wg1[i]; w2s[i] = wg2[i]; }
    __syncthreads();
    float s1[16], s2[16];
    #pragma unroll
    for (int o = 0; o < 16; o++) { s1[o] = 0.f; s2[o] = 0.f; }
    s16x8 xs[8];
    const float* xp = x + (size_t)n * 204800 + v * T_ + t;
    #pragma unroll
    for (int c = 0; c < 64; c++) {
        float xv = xp[(size_t)c * VT_];
        xs[c >> 3][c & 7] = (short)f2bf(xv);
        #pragma unroll
        for (int o = 0; o < 16; o++) {
            s1[o] = fmaf(w1s[o*64+c], xv, s1[o]);
            s2[o] = fmaf(w2s[o*64+c], xv, s2[o]);
        }
    }
    size_t abase = (size_t)n * 51200 + v * T_ + t;
    #pragma unroll
    for (int o = 0; o < 16; o++) {
        a1[abase + (size_t)o * VT_] = f2bf(s1[o]);
        a2[abase + (size_t)o * VT_] = f2bf(s2[o]);
    }
    ushort_t* cp = xb + (size_t)(n * VT_ + v * T_ + t) * 64;
    #pragma unroll
    for (int ch = 0; ch < 8; ch++) *(s16x8*)(cp + ch * 8) = xs[ch];
}

// ---------------- k_g: g = softmax(a1^T a2), fp32 (d_out) + bf16 copy (stride-640 pad) ----------------
__global__ __launch_bounds__(256) void k_g(const ushort_t* __restrict__ a1,
        const ushort_t* __restrict__ a2, float* __restrict__ g,
        ushort_t* __restrict__ gb) {
    int n = blockIdx.x >> 3; int t0 = (blockIdx.x & 7) * 16;
    __shared__ float A1s[6400], A2s[6400]; // [o][v][tt]
    for (int i = threadIdx.x; i < 6400; i += 256) {
        int o = i / 400; int r = i % 400; int v = r >> 4; int tt = r & 15;
        size_t ga = (size_t)n * 51200 + (size_t)o * VT_ + v * T_ + t0 + tt;
        A1s[i] = bf2f(a1[ga]);
        A2s[i] = bf2f(a2[ga]);
    }
    __syncthreads();
    for (int r = threadIdx.x; r < 400; r += 256) {
        int v = r >> 4; int tt = r & 15;
        float a1r[16];
        #pragma unroll
        for (int o = 0; o < 16; o++) a1r[o] = A1s[o*400 + v*16 + tt];
        float gr[25];
        float mx = -1e30f;
        for (int u = 0; u < 25; u++) {
            float s = 0.f;
            #pragma unroll
            for (int o = 0; o < 16; o++) s = fmaf(a1r[o], A2s[o*400 + u*16 + tt], s);
            gr[u] = s; mx = fmaxf(mx, s);
        }
        float sum = 0.f;
        for (int u = 0; u < 25; u++) { gr[u] = __expf(gr[u] - mx); sum += gr[u]; }
        float inv = 1.f / sum;
        float* gp = g + ((size_t)(n * T_ + t0 + tt) * V_ + v) * V_;
        ushort_t* gbp = gb + (size_t)(n * T_ + t0 + tt) * 640 + v * 25;
        for (int u = 0; u < 25; u++) {
            float val = gr[u] * inv;
            gp[u] = val;
            gbp[u] = f2bf(val);
        }
    }
}

// ---------------- all weight concats -> bf16 (one launch) ----------------
__global__ void k_wcat(const float* __restrict__ w11, const float* __restrict__ w12,
        const float* __restrict__ w21, const float* __restrict__ w22,
        const float* __restrict__ w31, const float* __restrict__ w32,
        ushort_t* __restrict__ Wc) {
    int i = blockIdx.x * 256 + threadIdx.x; // 352*256 = 90112 exact
    float v;
    if (i < 8192) {
        int o = i >> 7, k = i & 127;
        v = (k < 64) ? w11[o * 64 + k] : w12[o * 64 + k - 64];
    } else if (i < 24576) {
        int j = i - 8192; int o = j >> 7, k = j & 127;
        v = (k < 64) ? w21[o * 64 + k] : w22[o * 64 + k - 64];
    } else {
        int j = i - 24576; int o = j >> 8, k = j & 255;
        v = (k < 128) ? w31[o * 128 + k] : w32[o * 128 + k - 128];
    }
    Wc[i] = f2bf(v);
}

// ---------------- fused [BN+ReLU] + MP + MFMA GEMM ----------------
// m' = t*25 + v ordering. Tile = 100 rows (4 full t-groups x 25 v), o-tile OT.
// B = [ MP(yBN) | yBN ], A = Wc rows. TOUT=0: y [m'][OT*NO]; TOUT=2: y [O=256][m'].
template<int C, bool BNB, int NO, int OT, bool XBSRC, int TOUT>
__global__ __launch_bounds__(256) void k_fgemm(
        const ushort_t* __restrict__ Wc, const ushort_t* __restrict__ ysrc,
        const ushort_t* __restrict__ gb,
        const float* __restrict__ bns, const float* __restrict__ bnb,
        ushort_t* __restrict__ yt,
        float* __restrict__ psum, float* __restrict__ psq) {
    constexpr int K2 = 2 * C;
    constexpr int CHUNKS = K2 / 128;       // 1 (C=64) or 2 (C=128)
    constexpr int NOF = OT / 64;           // o-frags per wave
    constexpr int ABYTES = OT * 128 * 2;   // A chunk: [OT][128 cols]
    __shared__ __align__(16) char smem[ABYTES + 12800 + 14336 + 5120];
    char* A_  = smem;                      // [OT][16 chunks of 16B], swz by o&7
    char* YS  = smem + ABYTES;             // [100][8 chunks], swz by yr&7
    char* MPo = YS + 12800;                // [112][8 chunks], swz by r&7
    char* GS  = MPo + 14336;               // [4][640] bf16

    int n = blockIdx.y;
    int mb = blockIdx.x / NO, ob = blockIdx.x % NO;
    int m0 = mb * 100, o0 = ob * OT, tb = mb * 4;
    int tid = threadIdx.x, w = tid >> 6, lane = tid & 63;
    int l15 = lane & 15, g4 = lane >> 4;

    // stage Gs (4 t-groups x 640 bf16, incl. pad)
    for (int i = tid; i < 320; i += 256) {
        int tl = i / 80, q = i % 80;
        gload16(gb + ((size_t)(n * 128 + tb + tl)) * 640 + q * 8, GS + i * 16);
    }

    f32x4 acc[NOF][7] = {};

    for (int kc = 0; kc < CHUNKS; kc++) {
        if (kc) __syncthreads();
        // A stage (async, source-swizzled)
        for (int i = tid; i < OT * 16; i += 256) {
            int o = i >> 4, cc = i & 15;
            int cg = cc ^ (o & 7);
            int kreal = (cg < 8) ? (kc * 64 + cg * 8) : (C + kc * 64 + (cg - 8) * 8);
            gload16(Wc + (size_t)(o0 + o) * K2 + kreal, A_ + i * 16);
        }
        // Ys stage (reg, +BN+ReLU), swizzled ds_write
        for (int i = tid; i < 800; i += 256) {
            int yr = i >> 3, cc = i & 7;
            size_t saddr;
            if (XBSRC) {
                int t = tb + yr / 25, v = yr % 25;
                saddr = (size_t)n * 204800 + (size_t)(v * 128 + t) * 64 + cc * 8;
            } else {
                saddr = ((size_t)n * VT_ + m0 + yr) * C + kc * 64 + cc * 8;
            }
            s16x8 vv = *(const s16x8*)(ysrc + saddr);
            if (BNB) {
                int obx = kc * 64 + cc * 8;
                #pragma unroll
                for (int j = 0; j < 8; j++) {
                    float f = fmaf(bf2f((ushort_t)vv[j]), bns[obx + j], bnb[obx + j]);
                    vv[j] = (short)f2bf(fmaxf(f, 0.f));
                }
            }
            *(s16x8*)(YS + (yr * 8 + (cc ^ (yr & 7))) * 16) = vv;
        }
        __syncthreads();
        // MP: 160 items = 4 tl x 5 vg x 8 c8 ; each: 5 rows x 8 cols
        if (tid < 160) {
            int c8 = tid & 7, vg = (tid >> 3) % 5, tl = tid / 40;
            float macc[5][8] = {};
            const ushort_t* gsl = (const ushort_t*)GS + tl * 640;
            for (int u = 0; u < 25; u++) {
                int yr = tl * 25 + u;
                s16x8 yv = *(const s16x8*)(YS + (yr * 8 + (c8 ^ (yr & 7))) * 16);
                float yf[8];
                #pragma unroll
                for (int k = 0; k < 8; k++) yf[k] = bf2f((ushort_t)yv[k]);
                #pragma unroll
                for (int j = 0; j < 5; j++) {
                    float gv = bf2f(gsl[(vg * 5 + j) * 25 + u]);
                    #pragma unroll
                    for (int k = 0; k < 8; k++)
                        macc[j][k] = fmaf(gv, yf[k], macc[j][k]);
                }
            }
            #pragma unroll
            for (int j = 0; j < 5; j++) {
                int r = tl * 25 + vg * 5 + j;
                s16x8 pk;
                #pragma unroll
                for (int k = 0; k < 8; k++) pk[k] = (short)f2bf(macc[j][k]);
                *(s16x8*)(MPo + (r * 8 + (c8 ^ (r & 7))) * 16) = pk;
            }
        }
        __syncthreads();
        // MFMA: pass 0 = MP half, pass 1 = Y half
        #pragma unroll
        for (int pass = 0; pass < 2; pass++) {
            #pragma unroll
            for (int kk = 0; kk < 2; kk++) {
                s16x8 bF[7];
                #pragma unroll
                for (int mi = 0; mi < 7; mi++) {
                    int r = mi * 16 + l15;
                    int rr = (pass == 1 && r >= 100) ? 99 : r;
                    const char* bsrc = pass ? YS : MPo;
                    bF[mi] = *(const s16x8*)(bsrc + (rr * 8 + ((kk * 4 + g4) ^ (rr & 7))) * 16);
                }
                #pragma unroll
                for (int i = 0; i < NOF; i++) {
                    int o_loc = (w * NOF + i) * 16 + l15;
                    int ac = (pass * 8 + kk * 4 + g4) ^ (o_loc & 7);
                    s16x8 aF = *(const s16x8*)(A_ + (o_loc * 16 + ac) * 16);
                    #pragma unroll
                    for (int mi = 0; mi < 7; mi++)
                        acc[i][mi] = __builtin_amdgcn_mfma_f32_16x16x32_bf16(
                            aF, bF[mi], acc[i][mi], 0, 0, 0);
                }
            }
        }
    }
    // BN partial stats (mask pad cols 100-111 in mi=6)
    int p = n * 32 + mb;
    #pragma unroll
    for (int i = 0; i < NOF; i++) {
        #pragma unroll
        for (int b = 0; b < 4; b++) {
            float ss = 0.f, qq = 0.f;
            #pragma unroll
            for (int mi = 0; mi < 7; mi++) {
                float v0 = acc[i][mi][b];
                if (mi == 6 && l15 >= 4) v0 = 0.f;
                ss += v0; qq = fmaf(v0, v0, qq);
            }
            #pragma unroll
            for (int msk = 1; msk < 16; msk <<= 1) {
                ss += __shfl_xor(ss, msk, 16);
                qq += __shfl_xor(qq, msk, 16);
            }
            if (l15 == 0) {
                int o = o0 + (w * NOF + i) * 16 + g4 * 4 + b;
                psum[(size_t)o * 2048 + p] = ss;
                psq [(size_t)o * 2048 + p] = qq;
            }
        }
    }
    __syncthreads();
    if (TOUT == 0) {
        constexpr int OP = OT + 8;
        ushort_t* Lw = (ushort_t*)smem;   // [100][OP]
        #pragma unroll
        for (int i = 0; i < NOF; i++)
            #pragma unroll
            for (int mi = 0; mi < 7; mi++) {
                int r = mi * 16 + l15;
                if (r < 100) {
                    #pragma unroll
                    for (int b = 0; b < 4; b++)
                        Lw[r * OP + (w * NOF + i) * 16 + g4 * 4 + b] = f2bf(acc[i][mi][b]);
                }
            }
        __syncthreads();
        for (int i = tid; i < 100 * (OT / 8); i += 256) {
            int r = i / (OT / 8), oc = i % (OT / 8);
            s16x8 pk = *(const s16x8*)(Lw + r * OP + oc * 8);
            *(s16x8*)(yt + ((size_t)n * VT_ + m0 + r) * (OT * NO) + o0 + oc * 8) = pk;
        }
    } else {
        ushort_t* Lw = (ushort_t*)smem;   // [OT][112]
        #pragma unroll
        for (int i = 0; i < NOF; i++)
            #pragma unroll
            for (int mi = 0; mi < 7; mi++) {
                int r = mi * 16 + l15;
                #pragma unroll
                for (int b = 0; b < 4; b++)
                    Lw[((w * NOF + i) * 16 + g4 * 4 + b) * 112 + r] = f2bf(acc[i][mi][b]);
            }
        __syncthreads();
        for (int i = tid; i < OT * 25; i += 256) {
            int ol = i / 25, mc = i % 25;
            s16x4 pk = *(const s16x4*)(Lw + ol * 112 + mc * 4);
            *(s16x4*)(yt + ((size_t)(n * 256 + o0 + ol)) * VT_ + m0 + mc * 4) = pk;
        }
    }
}

// ---------------- finalize per-channel stats -> scale/shift arrays ----------------
__global__ __launch_bounds__(256) void k_stats(const float* __restrict__ psum,
        const float* __restrict__ psq, const float* __restrict__ gamma,
        const float* __restrict__ beta, float* __restrict__ bns,
        float* __restrict__ bnb) {
    int o = blockIdx.x;
    float s = 0.f, q = 0.f;
    for (int i = threadIdx.x; i < 2048; i += 256) {
        s += psum[(size_t)o*2048+i]; q += psq[(size_t)o*2048+i];
    }
    __shared__ float rs[256], rq[256];
    rs[threadIdx.x] = s; rq[threadIdx.x] = q;
    __syncthreads();
    for (int st = 128; st > 0; st >>= 1) {
        if (threadIdx.x < st) { rs[threadIdx.x] += rs[threadIdx.x+st]; rq[threadIdx.x] += rq[threadIdx.x+st]; }
        __syncthreads();
    }
    if (threadIdx.x == 0) {
        float mean = rs[0] / NVTF_;
        float var = rq[0] / NVTF_ - mean * mean;
        float scale = gamma[o] * rsqrtf(var + 1e-5f);
        bns[o] = scale;
        bnb[o] = beta[o] - mean * scale;
    }
}

// ---------------- final BN+ReLU + (t,v)->(v,t) transpose: y3 [O][m'] -> fp32 xout [O][v][t] ----------------
__global__ __launch_bounds__(256) void k_bnf(const ushort_t* __restrict__ y3,
        const float* __restrict__ bns, const float* __restrict__ bnb,
        float* __restrict__ xout) {
    __shared__ __align__(16) ushort_t L[8 * VT_];
    int n = blockIdx.y, oc = blockIdx.x;   // 64 x 32
    size_t base = (size_t)(n * 256 + oc * 8) * VT_;
    for (int i = threadIdx.x; i < 3200; i += 256)
        gload16(y3 + base + (size_t)i * 8, (char*)L + i * 16);
    __syncthreads();
    for (int i = threadIdx.x; i < 6400; i += 256) {
        int t4 = i & 31, v = (i >> 5) % 25, o = i / 800;
        int og = oc * 8 + o;
        float sc = bns[og], sh = bnb[og];
        int lb = o * VT_ + v;
        float4 f;
        f.x = fmaxf(fmaf(bf2f(L[lb + (t4*4+0)*25]), sc, sh), 0.f);
        f.y = fmaxf(fmaf(bf2f(L[lb + (t4*4+1)*25]), sc, sh), 0.f);
        f.z = fmaxf(fmaf(bf2f(L[lb + (t4*4+2)*25]), sc, sh), 0.f);
        f.w = fmaxf(fmaf(bf2f(L[lb + (t4*4+3)*25]), sc, sh), 0.f);
        *(float4*)(xout + (size_t)(n * 256 + og) * VT_ + v * T_ + t4 * 4) = f;
    }
}

extern "C" void kernel_launch(void* const* d_in, const int* in_sizes, int n_in,
                              void* d_out, int out_size, void* d_ws, size_t ws_size,
                              hipStream_t stream) {
    const float* x   = (const float*)d_in[0];
    const float* wg1 = (const float*)d_in[1];
    const float* wg2 = (const float*)d_in[2];
    const float* w11 = (const float*)d_in[3];
    const float* w12 = (const float*)d_in[4];
    const float* ga1 = (const float*)d_in[5];
    const float* be1 = (const float*)d_in[6];
    const float* w21 = (const float*)d_in[7];
    const float* w22 = (const float*)d_in[8];
    const float* ga2 = (const float*)d_in[9];
    const float* be2 = (const float*)d_in[10];
    const float* w31 = (const float*)d_in[11];
    const float* w32 = (const float*)d_in[12];
    const float* ga3 = (const float*)d_in[13];
    const float* be3 = (const float*)d_in[14];

    float* xout = (float*)d_out;               // (64,256,25,128) fp32
    float* gout = xout + 52428800;             // (64,128,25,25) fp32

    float* ws = (float*)d_ws;
    ushort_t* xb  = (ushort_t*)(ws + 0);          // 13,107,200 us [v*T+t][64]
    ushort_t* a1  = (ushort_t*)(ws + 6553600);    // 3,276,800 us
    ushort_t* a2  = (ushort_t*)(ws + 8192000);    // 3,276,800 us
    ushort_t* y1  = (ushort_t*)(ws + 9830400);    // 13,107,200 us [m'][64]
    ushort_t* y2  = (ushort_t*)(ws + 16384000);   // 26,214,400 us [m'][128]
    ushort_t* y3  = (ushort_t*)(ws + 29491200);   // 52,428,800 us [O=256][m']
    ushort_t* gb  = (ushort_t*)(ws + 55705600);   // 5,242,880 us [n][t][640]
    float* psum = ws + 58327040;                  // 524,288 fl [o][2048]
    float* psq  = ws + 58851328;                  // 524,288 fl
    ushort_t* Wc = (ushort_t*)(ws + 59375616);    // 90,112 us
    float* bns  = ws + 59420672;                  // 256 fl
    float* bnb  = ws + 59420928;                  // 256 fl
    ushort_t* Wc1 = Wc, *Wc2 = Wc + 8192, *Wc3 = Wc + 24576;

    k_a<<<1600, 128, 0, stream>>>(x, wg1, wg2, a1, a2, xb);
    k_g<<<512, 256, 0, stream>>>(a1, a2, gout, gb);
    k_wcat<<<352, 256, 0, stream>>>(w11, w12, w21, w22, w31, w32, Wc);

    // layer 1: C=64 -> O=64 (no BN on input)
    k_fgemm<64, false, 1, 64, true, 0><<<dim3(32, 64), 256, 0, stream>>>(
        Wc1, xb, gb, nullptr, nullptr, y1, psum, psq);
    k_stats<<<64, 256, 0, stream>>>(psum, psq, ga1, be1, bns, bnb);

    // layer 2: C=64 -> O=128 (BN(y1) fused into staging)
    k_fgemm<64, true, 1, 128, false, 0><<<dim3(32, 64), 256, 0, stream>>>(
        Wc2, y1, gb, bns, bnb, y2, psum, psq);
    k_stats<<<128, 256, 0, stream>>>(psum, psq, ga2, be2, bns, bnb);

    // layer 3: C=128 -> O=256 (BN(y2) fused), output [O][m']
    k_fgemm<128, true, 2, 128, false, 2><<<dim3(64, 64), 256, 0, stream>>>(
        Wc3, y2, gb, bns, bnb, y3, psum, psq);
    k_stats<<<256, 256, 0, stream>>>(psum, psq, ga3, be3, bns, bnb);

    k_bnf<<<dim3(32, 64), 256, 0, stream>>>(y3, bns, bnb, xout);
}